// Round 1
// baseline (132.770 us; speedup 1.0000x reference)
//
#include <hip/hip_runtime.h>

#define NBOX 4000
#define NPAD 4096
#define BATCH 8
#define WPR 64          // 64-bit words per suppression row (padded stride)
#define MAXK 300

// Static device scratch (deterministic, no dependence on ws_size).
__device__ unsigned long long g_sup[BATCH][NBOX][WPR];   // ~16.4 MB
__device__ float4 g_sorted[BATCH][NPAD];                 // 512 KB
__device__ int g_nvalid[BATCH];

// ---------------------------------------------------------------------------
// Kernel 1: per-batch key build + bitonic sort (LDS) + gather sorted boxes.
// Key = (valid ? ~bits(fg) : 0xFFFFFFFF) << 32 | index  → ascending sort gives
// descending fg with ascending-index tie-break (matches stable argsort).
// ---------------------------------------------------------------------------
__global__ __launch_bounds__(1024) void sort_kernel(const float* __restrict__ props,
                                                    const float* __restrict__ scores) {
    const int b = blockIdx.x;
    const int tid = threadIdx.x;
    __shared__ unsigned long long keys[NPAD];
    __shared__ int s_cnt;
    if (tid == 0) s_cnt = 0;
    __syncthreads();

    int localc = 0;
    for (int n = tid; n < NPAD; n += 1024) {
        unsigned long long key = ~0ull;
        if (n < NBOX) {
            float fg = scores[((size_t)b * NBOX + n) * 2 + 1];
            const float* p = props + ((size_t)b * NBOX + n) * 4;
            float x1 = p[0], y1 = p[1], x2 = p[2], y2 = p[3];
            float w = __fsub_rn(x2, x1);
            float h = __fsub_rn(y2, y1);
            bool valid = (fg > 0.5f) && (w >= 16.0f) && (h >= 16.0f);
            unsigned int hi = valid ? ~__float_as_uint(fg) : 0xFFFFFFFFu;
            key = ((unsigned long long)hi << 32) | (unsigned int)n;
            if (valid) localc++;
        }
        keys[n] = key;
    }
    // wave-reduce valid count, one atomic per wave
    for (int off = 32; off > 0; off >>= 1) localc += __shfl_down(localc, off);
    if ((tid & 63) == 0) atomicAdd(&s_cnt, localc);

    // bitonic sort ascending over 4096 keys
    for (int k = 2; k <= NPAD; k <<= 1) {
        for (int j = k >> 1; j > 0; j >>= 1) {
            __syncthreads();
            for (int t = tid; t < NPAD; t += 1024) {
                int partner = t ^ j;
                if (partner > t) {
                    unsigned long long a = keys[t];
                    unsigned long long c = keys[partner];
                    bool up = ((t & k) == 0);
                    if ((a > c) == up) { keys[t] = c; keys[partner] = a; }
                }
            }
        }
    }
    __syncthreads();

    const int nv = s_cnt;
    if (tid == 0) g_nvalid[b] = nv;
    for (int p = tid; p < NPAD; p += 1024) {
        if (p < nv) {
            unsigned int idx = (unsigned int)(keys[p] & 0xFFFFFFFFull);
            const float4 box = *reinterpret_cast<const float4*>(props + ((size_t)b * NBOX + idx) * 4);
            g_sorted[b][p] = box;
        }
    }
}

// ---------------------------------------------------------------------------
// Kernel 2: suppression bitmask rows. Block = 64 lanes = one row i.
// Bit j of row i set iff j>i, j<nvalid, IoU(i,j) >= 0.5 (fp32 ops match ref
// exactly: no contraction thanks to __f*_rn; division is correctly rounded).
// ---------------------------------------------------------------------------
__global__ __launch_bounds__(64) void iou_kernel() {
    const int b = blockIdx.y;
    const int i = blockIdx.x;
    const int nv = g_nvalid[b];
    if (i >= nv) return;
    const int lane = threadIdx.x;

    const float4 bi = g_sorted[b][i];
    const float areai = __fmul_rn(__fsub_rn(bi.z, bi.x), __fsub_rn(bi.w, bi.y));
    const int W = (nv + 63) >> 6;

    unsigned long long myword = 0ull;
    for (int c = 0; c < W; ++c) {
        int j = (c << 6) + lane;
        bool pred = false;
        if (j < nv && j > i) {
            float4 bj = g_sorted[b][j];
            float areaj = __fmul_rn(__fsub_rn(bj.z, bj.x), __fsub_rn(bj.w, bj.y));
            float xi1 = fmaxf(bi.x, bj.x);
            float yi1 = fmaxf(bi.y, bj.y);
            float xi2 = fminf(bi.z, bj.z);
            float yi2 = fminf(bi.w, bj.w);
            float iw = fmaxf(__fsub_rn(xi2, xi1), 0.0f);
            float ih = fmaxf(__fsub_rn(yi2, yi1), 0.0f);
            float inter = __fmul_rn(iw, ih);
            float uni = __fsub_rn(__fadd_rn(areai, areaj), inter);
            pred = (inter / uni) >= 0.5f;
        }
        unsigned long long wd = __ballot(pred);
        if (lane == c) myword = wd;
    }
    g_sup[b][i][lane] = myword;   // lanes >= W store 0 (never consulted)
}

// ---------------------------------------------------------------------------
// Kernel 3: serial greedy scan, one wave per batch. removed-mask word w lives
// in lane w. Linear scan with double-buffered 16-row prefetch; early exit at
// 300 kept. Then write all 300 output rows (zero-padded).
// ---------------------------------------------------------------------------
__global__ __launch_bounds__(64) void nms_kernel(float* __restrict__ out) {
    const int b = blockIdx.x;
    const int lane = threadIdx.x;
    int nv = g_nvalid[b];
    if (nv > NBOX) nv = NBOX;

    __shared__ int sKept[MAXK];
    unsigned long long removed = 0ull;
    const unsigned long long* rowbase = &g_sup[b][0][0];
    int kept = 0;

    unsigned long long rA[16], rB[16];
#pragma unroll
    for (int u = 0; u < 16; ++u)
        rA[u] = (u < nv) ? rowbase[(size_t)u * WPR + lane] : 0ull;

    for (int base = 0; base < nv && kept < MAXK; base += 16) {
        // issue next chunk's loads (latency hidden under the serial chain)
#pragma unroll
        for (int u = 0; u < 16; ++u) {
            int nx = base + 16 + u;
            rB[u] = (nx < nv) ? rowbase[(size_t)nx * WPR + lane] : 0ull;
        }
#pragma unroll
        for (int u = 0; u < 16; ++u) {
            int i = base + u;
            if (i < nv && kept < MAXK) {
                unsigned long long wv = __shfl(removed, i >> 6);
                if (!((wv >> (i & 63)) & 1ull)) {
                    if (lane == 0) sKept[kept] = i;
                    kept++;
                    removed |= rA[u];
                }
            }
        }
#pragma unroll
        for (int u = 0; u < 16; ++u) rA[u] = rB[u];
    }
    __syncthreads();

    float4* outv = reinterpret_cast<float4*>(out) + (size_t)b * MAXK;
    for (int s = lane; s < MAXK; s += 64) {
        float4 v = make_float4(0.0f, 0.0f, 0.0f, 0.0f);
        if (s < kept) v = g_sorted[b][sKept[s]];
        outv[s] = v;
    }
}

extern "C" void kernel_launch(void* const* d_in, const int* in_sizes, int n_in,
                              void* d_out, int out_size, void* d_ws, size_t ws_size,
                              hipStream_t stream) {
    const float* props  = (const float*)d_in[0];   // (8,4000,4) f32
    const float* scores = (const float*)d_in[1];   // (8,4000,2) f32
    float* out = (float*)d_out;                    // (8,300,4) f32

    sort_kernel<<<BATCH, 1024, 0, stream>>>(props, scores);
    iou_kernel<<<dim3(NBOX, BATCH), 64, 0, stream>>>();
    nms_kernel<<<BATCH, 64, 0, stream>>>(out);
}